// Round 5
// baseline (203.035 us; speedup 1.0000x reference)
//
#include <hip/hip_runtime.h>

// NADE forward, B=512, D=1024, H=512, C=4.
// 3 kernels: k_prep_all (V->MFMA frags bf16, W^T*log2e, x^T),
//            k_state    (fused partial+prefix: running a-state, checkpoint every 32 d),
//            k_main     (checkpointed scan; 8 waves x 64-h slices; bf16 MFMA logits;
//                        in-lane softmax; one barrier per 2 d-steps).
// Preactivations in log2e-scaled domain: sigma = rcp(1+exp2(-a)).

#define Bv 512
#define Dv 1024
#define Hv 512
#define Cv 4
#define Kv 32
#define DCv 32   // Dv / Kv

#define L2E 1.4426950408889634f
#define LN2 0.6931471805599453f

typedef __attribute__((ext_vector_type(8))) short short8;
typedef __attribute__((ext_vector_type(4))) float f32x4;
typedef __attribute__((ext_vector_type(2))) float v2f;

__device__ __forceinline__ float fexp2(float x) { return __builtin_amdgcn_exp2f(x); }
__device__ __forceinline__ float flog2(float x) { return __builtin_amdgcn_logf(x); }
__device__ __forceinline__ float frcp(float x)  { return __builtin_amdgcn_rcpf(x); }

__device__ __forceinline__ v2f fma2(v2f a, v2f b, v2f c) {
#if __has_builtin(__builtin_elementwise_fma)
    return __builtin_elementwise_fma(a, b, c);
#else
    v2f r; r.x = fmaf(a.x, b.x, c.x); r.y = fmaf(a.y, b.y, c.y); return r;
#endif
}

// pack two f32 -> bf16x2 by truncation (1 v_perm_b32)
__device__ __forceinline__ unsigned bf16pk(float lo, float hi) {
    return __builtin_amdgcn_perm(__float_as_uint(hi), __float_as_uint(lo), 0x07060302u);
}
__device__ __forceinline__ unsigned short bf16rne(float f) {
    unsigned u = __float_as_uint(f);
    return (unsigned short)((u + 0x7FFFu + ((u >> 16) & 1u)) >> 16);
}

// ---- k_prep_all: 512 blocks.
//  [0,256):   V -> VtA4 MFMA A-fragments (bf16 RNE), d-tile of 4
//  [256,384): W -> WtL = W^T * log2e   (64x64 LDS tiles)
//  [384,512): x -> xt  = x^T           (64x64 LDS tiles)
__global__ __launch_bounds__(256) void k_prep_all(
        const float* __restrict__ V, const float* __restrict__ W,
        const float* __restrict__ x, unsigned short* __restrict__ VtA4,
        float* __restrict__ WtL, float* __restrict__ xt) {
    __shared__ char smem[17408];
    const int bid = blockIdx.x;
    if (bid < 256) {
        unsigned short* tile = (unsigned short*)smem;   // 16 KiB
        const int d0 = bid * 4;
        const int dd = threadIdx.x & 3;
        const int hb0 = threadIdx.x >> 2;
#pragma unroll
        for (int p = 0; p < 8; ++p) {
            int h = p * 64 + hb0;
            float4 v = *(const float4*)(V + ((size_t)h * Dv + d0 + dd) * Cv);
            int hb = h >> 5, q = (h >> 3) & 3, j = h & 7;
            int base = ((dd * 16 + hb) * 16 + q * 4) * 8 + j;
            tile[base + 0]  = bf16rne(v.x);
            tile[base + 8]  = bf16rne(v.y);
            tile[base + 16] = bf16rne(v.z);
            tile[base + 24] = bf16rne(v.w);
        }
        __syncthreads();
        uint4* dst = (uint4*)(VtA4 + (size_t)d0 * 2048);
        const uint4* src = (const uint4*)tile;
        for (int t = threadIdx.x; t < 1024; t += 256) dst[t] = src[t];
    } else {
        float (*t)[65] = (float (*)[65])smem;           // 64x65 = 16640 B
        const int mb   = (bid - 256) >> 7;              // 0: W, 1: x
        const int tile = (bid - 256) & 127;
        const int tr   = tile >> 4;
        const int tc   = tile & 15;
        const float* src = mb ? x : W;
        float* dst       = mb ? xt : WtL;
        const float scale = mb ? 1.0f : L2E;
        const int lx = threadIdx.x & 15;
        const int ly = threadIdx.x >> 4;
#pragma unroll
        for (int r = 0; r < 64; r += 16) {
            int row = r + ly;
            float4 v = *(const float4*)(src + (size_t)(tr * 64 + row) * Dv + tc * 64 + lx * 4);
            t[row][lx * 4 + 0] = v.x;
            t[row][lx * 4 + 1] = v.y;
            t[row][lx * 4 + 2] = v.z;
            t[row][lx * 4 + 3] = v.w;
        }
        __syncthreads();
#pragma unroll
        for (int r = 0; r < 64; r += 16) {
            int row = r + ly;
            float4 o = make_float4(t[lx * 4 + 0][row] * scale,
                                   t[lx * 4 + 1][row] * scale,
                                   t[lx * 4 + 2][row] * scale,
                                   t[lx * 4 + 3][row] * scale);
            *(float4*)(dst + (size_t)(tc * 64 + row) * 512 + tr * 64 + lx * 4) = o;
        }
    }
}

// ---- k_state: fused partial + prefix. 64 blocks (8 batches each) x 512 threads (h).
// Running a (scaled domain) over all D; store checkpoint A0[k][b][h] before chunk k.
__global__ __launch_bounds__(512) void k_state(
        const float* __restrict__ x, const float* __restrict__ WtL,
        const float* __restrict__ cb, float* __restrict__ A0) {
    __shared__ float xs[Dv * 8];   // 32 KiB
    const int bg = blockIdx.x;
    const int h  = threadIdx.x;
    for (int idx = threadIdx.x; idx < Dv * 8; idx += 512) {
        int d = idx & (Dv - 1);
        int g = idx >> 10;
        xs[d * 8 + g] = x[(size_t)(bg * 8 + g) * Dv + d];
    }
    __syncthreads();
    float cl = cb[h] * L2E;
    v2f run[4];
    run[0] = (v2f){cl, cl}; run[1] = (v2f){cl, cl};
    run[2] = (v2f){cl, cl}; run[3] = (v2f){cl, cl};
    const float* wp = WtL + h;
    for (int kk = 0; kk < Kv; ++kk) {
        float* a0p = A0 + ((size_t)kk * Bv + bg * 8) * Hv + h;
#pragma unroll
        for (int t = 0; t < 4; ++t) {
            a0p[(size_t)(2 * t) * Hv]     = run[t].x;
            a0p[(size_t)(2 * t + 1) * Hv] = run[t].y;
        }
        const float* wkk = wp + (size_t)kk * DCv * Hv;
#pragma unroll 8
        for (int j = 0; j < DCv; ++j) {
            float wv = wkk[(size_t)j * Hv];
            const float4 xa = *(const float4*)(xs + (kk * DCv + j) * 8);
            const float4 xb = *(const float4*)(xs + (kk * DCv + j) * 8 + 4);
            v2f wv2 = {wv, wv};
            run[0] = fma2((v2f){xa.x, xa.y}, wv2, run[0]);
            run[1] = fma2((v2f){xa.z, xa.w}, wv2, run[1]);
            run[2] = fma2((v2f){xb.x, xb.y}, wv2, run[2]);
            run[3] = fma2((v2f){xb.z, xb.w}, wv2, run[3]);
        }
    }
}

// ---- k_main: grid Kv*32 blocks of 512 (8 waves = 8 x 64-h slices) ----
__global__ __launch_bounds__(512, 8) void k_main(
        const float* __restrict__ xt, const float* __restrict__ bbias,
        const unsigned short* __restrict__ VtA4, const float* __restrict__ WtL,
        const float* __restrict__ A0, float* __restrict__ out) {
    const int k    = blockIdx.x >> 5;
    const int bg   = blockIdx.x & 31;
    const int wid  = threadIdx.x >> 6;   // 0..7: 64-h slice / epilogue role
    const int lane = threadIdx.x & 63;
    const int bl   = lane & 15;          // batch col (B-op) / class row (A-op)
    const int quad = lane >> 4;
    const int b    = bg * 16 + bl;
    const int d0   = k * DCv;
    const int stp  = (wid >> 1) & 1;     // which step of the pair this wave stores
    const bool isP = wid & 1;
    const bool active = wid < 4;

    __shared__ f32x4 red[2][2][8][64];   // 32 KiB double-buffered partials

    // a state: h = wid*64 + kb*32 + quad*8 + {0..7}, as v2f pairs
    v2f a2[8];
    {
        const float* ap = A0 + ((size_t)k * Bv + b) * Hv + wid * 64 + quad * 8;
#pragma unroll
        for (int kb = 0; kb < 2; ++kb)
#pragma unroll
            for (int t = 0; t < 4; ++t)
                a2[kb * 4 + t] = *(const v2f*)(ap + kb * 32 + 2 * t);
    }

    // clamp A-row index for lanes bl>=4 (their A rows are garbage-tolerated;
    // clamping keeps the address in-bounds)
    const int blc = (bl < 4) ? bl : 0;
    const unsigned short* vp = VtA4 + (((size_t)d0 * 16 + wid * 2) * 16 + quad * 4 + blc) * 8;
    const float* wp = WtL + (size_t)d0 * Hv + wid * 64 + quad * 8;
    const float* xp = xt + (size_t)d0 * Bv + b;
    const float* bp = bbias + (d0 + stp) * Cv;
    float* sp = out + (isP ? (size_t)Bv * Dv * Cv : (size_t)0)
                    + (size_t)b * Dv * Cv + (d0 + stp) * Cv;

    for (int i1 = 0; i1 < DCv / 2; ++i1) {
        float xdA = xp[0];
        float xdB = xp[Bv];
        float4 bbv = *(const float4*)bp;

        // ---- step A ----
        f32x4 accA = {0.f, 0.f, 0.f, 0.f};
#pragma unroll
        for (int kb = 0; kb < 2; ++kb) {
            union { unsigned u[4]; short8 s; } cv;
#pragma unroll
            for (int t = 0; t < 4; ++t) {
                v2f aa = a2[kb * 4 + t];
                v2f e; e.x = fexp2(-aa.x); e.y = fexp2(-aa.y);
                v2f q = e + 1.0f;
                cv.u[t] = bf16pk(frcp(q.x), frcp(q.y));
            }
            short8 af = *(const short8*)(vp + kb * 128);
            accA = __builtin_amdgcn_mfma_f32_16x16x32_bf16(af, cv.s, accA, 0, 0, 0);
        }
        v2f xA2 = {xdA, xdA};
#pragma unroll
        for (int kb = 0; kb < 2; ++kb)
#pragma unroll
            for (int t = 0; t < 4; ++t) {
                v2f wv = *(const v2f*)(wp + kb * 32 + 2 * t);
                a2[kb * 4 + t] = fma2(xA2, wv, a2[kb * 4 + t]);
            }

        // ---- step B ----
        f32x4 accB = {0.f, 0.f, 0.f, 0.f};
#pragma unroll
        for (int kb = 0; kb < 2; ++kb) {
            union { unsigned u[4]; short8 s; } cv;
#pragma unroll
            for (int t = 0; t < 4; ++t) {
                v2f aa = a2[kb * 4 + t];
                v2f e; e.x = fexp2(-aa.x); e.y = fexp2(-aa.y);
                v2f q = e + 1.0f;
                cv.u[t] = bf16pk(frcp(q.x), frcp(q.y));
            }
            short8 af = *(const short8*)(vp + 2048 + kb * 128);
            accB = __builtin_amdgcn_mfma_f32_16x16x32_bf16(af, cv.s, accB, 0, 0, 0);
        }
        v2f xB2 = {xdB, xdB};
#pragma unroll
        for (int kb = 0; kb < 2; ++kb)
#pragma unroll
            for (int t = 0; t < 4; ++t) {
                v2f wv = *(const v2f*)(wp + Hv + kb * 32 + 2 * t);
                a2[kb * 4 + t] = fma2(xB2, wv, a2[kb * 4 + t]);
            }

        // ---- cross-wave reduce: one barrier per pair ----
        red[i1 & 1][0][wid][lane] = accA;
        red[i1 & 1][1][wid][lane] = accB;
        __syncthreads();

        if (active) {
            f32x4 s = red[i1 & 1][stp][0][lane];
#pragma unroll
            for (int w8 = 1; w8 < 8; ++w8)
                s += red[i1 & 1][stp][w8][lane];
            float w0 = s.x + bbv.x;
            float w1 = s.y + bbv.y;
            float w2 = s.z + bbv.z;
            float w3 = s.w + bbv.w;
            if (!isP) {
                if (quad == 0) *(float4*)sp = make_float4(w0, w1, w2, w3);
            } else {
                float mx = fmaxf(fmaxf(w0, w1), fmaxf(w2, w3));
                float e0 = fexp2((w0 - mx) * L2E);
                float e1 = fexp2((w1 - mx) * L2E);
                float e2 = fexp2((w2 - mx) * L2E);
                float e3 = fexp2((w3 - mx) * L2E);
                float lse = mx + flog2(e0 + e1 + e2 + e3) * LN2;
                if (quad == 0)
                    *(float4*)sp = make_float4(w0 - lse, w1 - lse, w2 - lse, w3 - lse);
            }
        }

        vp += 2 * 2048;
        wp += 2 * Hv;
        xp += 2 * Bv;
        bp += 2 * Cv;
        sp += 2 * Cv;
    }
}

extern "C" void kernel_launch(void* const* d_in, const int* in_sizes, int n_in,
                              void* d_out, int out_size, void* d_ws, size_t ws_size,
                              hipStream_t stream) {
    const float* x  = (const float*)d_in[0];   // [B, D]
    const float* V  = (const float*)d_in[1];   // [H, D, C]
    const float* bb = (const float*)d_in[2];   // [D, C]
    const float* W  = (const float*)d_in[3];   // [H, D]
    const float* cb = (const float*)d_in[4];   // [1, H]
    float* out = (float*)d_out;                // y_hat [B*D*C] then p_hat

    char* ws = (char*)d_ws;
    unsigned short* VtA4 = (unsigned short*)ws;                 // 4 MiB
    float* WtL = (float*)(ws + (size_t)4 * 1024 * 1024);        // 2 MiB
    float* xt  = (float*)(ws + (size_t)6 * 1024 * 1024);        // 2 MiB
    float* A0  = (float*)(ws + (size_t)8 * 1024 * 1024);        // 32 MiB (K*B*H)

    k_prep_all<<<512, 256, 0, stream>>>(V, W, x, VtA4, WtL, xt);
    k_state<<<Bv / 8, 512, 0, stream>>>(x, WtL, cb, A0);
    k_main<<<Kv * 32, 512, 0, stream>>>(xt, bb, VtA4, WtL, A0, out);
}

// Round 6
// 194.007 us; speedup vs baseline: 1.0465x; 1.0465x over previous
//
#include <hip/hip_runtime.h>

// NADE forward, B=512, D=1024, H=512, C=4.
// 3 kernels: k_prep_all (V->MFMA frags bf16, W^T*log2e, x^T),
//            k_state    (fused partial+prefix, 256 blocks x 2 batches),
//            k_main     (checkpointed scan; 2 waves x 256-h slices; bf16 MFMA
//                        logits; in-lane softmax; one 2-wave barrier per 2 d).
// Preactivations in log2e-scaled domain: sigma = rcp(1+exp2(-a)).

#define Bv 512
#define Dv 1024
#define Hv 512
#define Cv 4
#define Kv 32
#define DCv 32   // Dv / Kv

#define L2E 1.4426950408889634f
#define LN2 0.6931471805599453f

typedef __attribute__((ext_vector_type(8))) short short8;
typedef __attribute__((ext_vector_type(4))) float f32x4;
typedef __attribute__((ext_vector_type(2))) float v2f;

__device__ __forceinline__ float fexp2(float x) { return __builtin_amdgcn_exp2f(x); }
__device__ __forceinline__ float flog2(float x) { return __builtin_amdgcn_logf(x); }
__device__ __forceinline__ float frcp(float x)  { return __builtin_amdgcn_rcpf(x); }

__device__ __forceinline__ v2f fma2(v2f a, v2f b, v2f c) {
#if __has_builtin(__builtin_elementwise_fma)
    return __builtin_elementwise_fma(a, b, c);
#else
    v2f r; r.x = fmaf(a.x, b.x, c.x); r.y = fmaf(a.y, b.y, c.y); return r;
#endif
}

// pack two f32 -> bf16x2 by truncation (1 v_perm_b32); lo in low half
__device__ __forceinline__ unsigned bf16pk(float lo, float hi) {
    return __builtin_amdgcn_perm(__float_as_uint(hi), __float_as_uint(lo), 0x07060302u);
}
__device__ __forceinline__ unsigned short bf16rne(float f) {
    unsigned u = __float_as_uint(f);
    return (unsigned short)((u + 0x7FFFu + ((u >> 16) & 1u)) >> 16);
}

// ---- k_prep_all: 512 blocks.
//  [0,256):   V -> VtA4 MFMA A-fragments (bf16 RNE), d-tile of 4
//  [256,384): W -> WtL = W^T * log2e   (64x64 LDS tiles)
//  [384,512): x -> xt  = x^T           (64x64 LDS tiles)
__global__ __launch_bounds__(256) void k_prep_all(
        const float* __restrict__ V, const float* __restrict__ W,
        const float* __restrict__ x, unsigned short* __restrict__ VtA4,
        float* __restrict__ WtL, float* __restrict__ xt) {
    __shared__ char smem[17408];
    const int bid = blockIdx.x;
    if (bid < 256) {
        unsigned short* tile = (unsigned short*)smem;   // 16 KiB
        const int d0 = bid * 4;
        const int dd = threadIdx.x & 3;
        const int hb0 = threadIdx.x >> 2;
#pragma unroll
        for (int p = 0; p < 8; ++p) {
            int h = p * 64 + hb0;
            float4 v = *(const float4*)(V + ((size_t)h * Dv + d0 + dd) * Cv);
            int hb = h >> 5, q = (h >> 3) & 3, j = h & 7;
            int base = ((dd * 16 + hb) * 16 + q * 4) * 8 + j;
            tile[base + 0]  = bf16rne(v.x);
            tile[base + 8]  = bf16rne(v.y);
            tile[base + 16] = bf16rne(v.z);
            tile[base + 24] = bf16rne(v.w);
        }
        __syncthreads();
        uint4* dst = (uint4*)(VtA4 + (size_t)d0 * 2048);
        const uint4* src = (const uint4*)tile;
        for (int t = threadIdx.x; t < 1024; t += 256) dst[t] = src[t];
    } else {
        float (*t)[65] = (float (*)[65])smem;           // 64x65 floats
        const int mb   = (bid - 256) >> 7;              // 0: W, 1: x
        const int tile = (bid - 256) & 127;
        const int tr   = tile >> 4;
        const int tc   = tile & 15;
        const float* src = mb ? x : W;
        float* dst       = mb ? xt : WtL;
        const float scale = mb ? 1.0f : L2E;
        const int lx = threadIdx.x & 15;
        const int ly = threadIdx.x >> 4;
#pragma unroll
        for (int r = 0; r < 64; r += 16) {
            int row = r + ly;
            float4 v = *(const float4*)(src + (size_t)(tr * 64 + row) * Dv + tc * 64 + lx * 4);
            t[row][lx * 4 + 0] = v.x;
            t[row][lx * 4 + 1] = v.y;
            t[row][lx * 4 + 2] = v.z;
            t[row][lx * 4 + 3] = v.w;
        }
        __syncthreads();
#pragma unroll
        for (int r = 0; r < 64; r += 16) {
            int row = r + ly;
            float4 o = make_float4(t[lx * 4 + 0][row] * scale,
                                   t[lx * 4 + 1][row] * scale,
                                   t[lx * 4 + 2][row] * scale,
                                   t[lx * 4 + 3][row] * scale);
            *(float4*)(dst + (size_t)(tc * 64 + row) * 512 + tr * 64 + lx * 4) = o;
        }
    }
}

// ---- k_state: fused partial + prefix. 256 blocks (2 batches) x 512 threads (h).
__global__ __launch_bounds__(512) void k_state(
        const float* __restrict__ x, const float* __restrict__ WtL,
        const float* __restrict__ cb, float* __restrict__ A0) {
    __shared__ float xs[Dv * 2];   // [d][g], 8 KiB
    const int bg = blockIdx.x;     // batch pair
    const int h  = threadIdx.x;
#pragma unroll
    for (int p = 0; p < 4; ++p) {
        int idx = p * 512 + threadIdx.x;    // 0..2047
        int g = idx >> 10;
        int d = idx & (Dv - 1);
        xs[d * 2 + g] = x[(size_t)(bg * 2 + g) * Dv + d];
    }
    __syncthreads();
    float cl = cb[h] * L2E;
    v2f run = {cl, cl};
    const float* wp = WtL + h;
    for (int kk = 0; kk < Kv; ++kk) {
        float* a0p = A0 + ((size_t)kk * Bv + bg * 2) * Hv + h;
        a0p[0]  = run.x;
        a0p[Hv] = run.y;
        const float* wkk = wp + (size_t)kk * DCv * Hv;
        const v2f* xk = (const v2f*)(xs + kk * DCv * 2);
#pragma unroll 8
        for (int j = 0; j < DCv; ++j) {
            float wv = wkk[(size_t)j * Hv];
            run = fma2(xk[j], (v2f){wv, wv}, run);
        }
    }
}

// ---- k_main: grid Kv*32 blocks of 128 (2 waves = 2 x 256-h slices) ----
__global__ __launch_bounds__(128) void k_main(
        const float* __restrict__ xt, const float* __restrict__ bbias,
        const unsigned short* __restrict__ VtA4, const float* __restrict__ WtL,
        const float* __restrict__ A0, float* __restrict__ out) {
    const int k    = blockIdx.x >> 5;    // chunk
    const int bg   = blockIdx.x & 31;    // 16-batch group
    const int wv   = threadIdx.x >> 6;   // h-half (0: h<256) AND step role
    const int lane = threadIdx.x & 63;
    const int bl   = lane & 15;          // batch col (B-op) / class row (A-op)
    const int quad = lane >> 4;
    const int b    = bg * 16 + bl;
    const int d0   = k * DCv;

    __shared__ f32x4 red[2][2][2][64];   // [dbuf][step][hhalf][lane], 8 KiB

    // a state: h = wv*256 + kb*32 + quad*8 + {0..7}, as v2f pairs
    v2f a2[32];
    {
        const float* ap = A0 + ((size_t)k * Bv + b) * Hv + wv * 256 + quad * 8;
#pragma unroll
        for (int kb = 0; kb < 8; ++kb)
#pragma unroll
            for (int t = 0; t < 4; ++t)
                a2[kb * 4 + t] = *(const v2f*)(ap + kb * 32 + 2 * t);
    }

    const int blc = (bl < 4) ? bl : 0;   // clamp A-row (garbage rows discarded)
    const unsigned short* vp = VtA4 + (((size_t)d0 * 16 + wv * 8) * 16 + quad * 4 + blc) * 8;
    const float* wp = WtL + (size_t)d0 * Hv + wv * 256 + quad * 8;
    const float* xp = xt + (size_t)d0 * Bv + b;
    const float* bp = bbias + (d0 + wv) * Cv;
    float* sy = out + (size_t)b * Dv * Cv + (d0 + wv) * Cv;
    float* spp = sy + (size_t)Bv * Dv * Cv;

    for (int i1 = 0; i1 < DCv / 2; ++i1) {
        float xdA = xp[0];
        float xdB = xp[Bv];
        float4 bbv = *(const float4*)bp;   // this wave's step's bias

        // ---- step A: sigmoid + pack + MFMA over 8 h-blocks ----
        f32x4 accA = {0.f, 0.f, 0.f, 0.f};
#pragma unroll
        for (int kb = 0; kb < 8; ++kb) {
            union { unsigned u[4]; short8 s; } cv;
#pragma unroll
            for (int t = 0; t < 4; ++t) {
                v2f aa = a2[kb * 4 + t];
                v2f e; e.x = fexp2(-aa.x); e.y = fexp2(-aa.y);
                v2f q = e + 1.0f;
                cv.u[t] = bf16pk(frcp(q.x), frcp(q.y));
            }
            short8 af = *(const short8*)(vp + kb * 128);
            accA = __builtin_amdgcn_mfma_f32_16x16x32_bf16(af, cv.s, accA, 0, 0, 0);
        }
        v2f xA2 = {xdA, xdA};
#pragma unroll
        for (int kb = 0; kb < 8; ++kb)
#pragma unroll
            for (int t = 0; t < 4; ++t)
                a2[kb * 4 + t] = fma2(xA2, *(const v2f*)(wp + kb * 32 + 2 * t), a2[kb * 4 + t]);

        // ---- step B ----
        f32x4 accB = {0.f, 0.f, 0.f, 0.f};
#pragma unroll
        for (int kb = 0; kb < 8; ++kb) {
            union { unsigned u[4]; short8 s; } cv;
#pragma unroll
            for (int t = 0; t < 4; ++t) {
                v2f aa = a2[kb * 4 + t];
                v2f e; e.x = fexp2(-aa.x); e.y = fexp2(-aa.y);
                v2f q = e + 1.0f;
                cv.u[t] = bf16pk(frcp(q.x), frcp(q.y));
            }
            short8 af = *(const short8*)(vp + 2048 + kb * 128);
            accB = __builtin_amdgcn_mfma_f32_16x16x32_bf16(af, cv.s, accB, 0, 0, 0);
        }
        v2f xB2 = {xdB, xdB};
#pragma unroll
        for (int kb = 0; kb < 8; ++kb)
#pragma unroll
            for (int t = 0; t < 4; ++t)
                a2[kb * 4 + t] = fma2(xB2, *(const v2f*)(wp + Hv + kb * 32 + 2 * t), a2[kb * 4 + t]);

        // ---- 2-wave reduce: one barrier per pair ----
        red[i1 & 1][0][wv][lane] = accA;
        red[i1 & 1][1][wv][lane] = accB;
        __syncthreads();

        // wave wv handles step wv's epilogue (y AND p)
        f32x4 s = red[i1 & 1][wv][0][lane] + red[i1 & 1][wv][1][lane];
        float w0 = s.x + bbv.x;
        float w1 = s.y + bbv.y;
        float w2 = s.z + bbv.z;
        float w3 = s.w + bbv.w;
        float mx = fmaxf(fmaxf(w0, w1), fmaxf(w2, w3));
        float e0 = fexp2((w0 - mx) * L2E);
        float e1 = fexp2((w1 - mx) * L2E);
        float e2 = fexp2((w2 - mx) * L2E);
        float e3 = fexp2((w3 - mx) * L2E);
        float lse = mx + flog2(e0 + e1 + e2 + e3) * LN2;
        if (quad == 0) {
            *(float4*)sy  = make_float4(w0, w1, w2, w3);
            *(float4*)spp = make_float4(w0 - lse, w1 - lse, w2 - lse, w3 - lse);
        }

        vp += 2 * 2048;    // 2 d-steps
        wp += 2 * Hv;
        xp += 2 * Bv;
        bp += 2 * Cv;
        sy += 2 * Cv;
        spp += 2 * Cv;
    }
}

extern "C" void kernel_launch(void* const* d_in, const int* in_sizes, int n_in,
                              void* d_out, int out_size, void* d_ws, size_t ws_size,
                              hipStream_t stream) {
    const float* x  = (const float*)d_in[0];   // [B, D]
    const float* V  = (const float*)d_in[1];   // [H, D, C]
    const float* bb = (const float*)d_in[2];   // [D, C]
    const float* W  = (const float*)d_in[3];   // [H, D]
    const float* cb = (const float*)d_in[4];   // [1, H]
    float* out = (float*)d_out;                // y_hat [B*D*C] then p_hat

    char* ws = (char*)d_ws;
    unsigned short* VtA4 = (unsigned short*)ws;                 // 4 MiB
    float* WtL = (float*)(ws + (size_t)4 * 1024 * 1024);        // 2 MiB
    float* xt  = (float*)(ws + (size_t)6 * 1024 * 1024);        // 2 MiB
    float* A0  = (float*)(ws + (size_t)8 * 1024 * 1024);        // 32 MiB (K*B*H)

    k_prep_all<<<512, 256, 0, stream>>>(V, W, x, VtA4, WtL, xt);
    k_state<<<Bv / 2, 512, 0, stream>>>(x, WtL, cb, A0);
    k_main<<<Kv * 32, 128, 0, stream>>>(xt, bb, VtA4, WtL, A0, out);
}

// Round 7
// 175.351 us; speedup vs baseline: 1.1579x; 1.1064x over previous
//
#include <hip/hip_runtime.h>
#include <hip/hip_fp16.h>

// NADE forward, B=512, D=1024, H=512, C=4.
// 4 kernels: k_prep_all (V->MFMA frags bf16, W^T*log2e, x^T),
//            k_partial  (chunk partial sums, half, 4096 wide blocks),
//            k_prefix   (in-place exclusive prefix over 64 chunks, half),
//            k_main     (checkpointed scan; 2 waves x 256-h; bf16 MFMA logits;
//                        in-lane softmax; Kv=64 chunks -> 4 waves/SIMD).
// Preactivations in log2e-scaled domain: sigma = rcp(1+exp2(-a)).

#define Bv 512
#define Dv 1024
#define Hv 512
#define Cv 4
#define Kv 64
#define DCv 16   // Dv / Kv

#define L2E 1.4426950408889634f
#define LN2 0.6931471805599453f

typedef __attribute__((ext_vector_type(8))) short short8;
typedef __attribute__((ext_vector_type(4))) float f32x4;
typedef __attribute__((ext_vector_type(2))) float v2f;

__device__ __forceinline__ float fexp2(float x) { return __builtin_amdgcn_exp2f(x); }
__device__ __forceinline__ float flog2(float x) { return __builtin_amdgcn_logf(x); }
__device__ __forceinline__ float frcp(float x)  { return __builtin_amdgcn_rcpf(x); }

__device__ __forceinline__ v2f fma2(v2f a, v2f b, v2f c) {
#if __has_builtin(__builtin_elementwise_fma)
    return __builtin_elementwise_fma(a, b, c);
#else
    v2f r; r.x = fmaf(a.x, b.x, c.x); r.y = fmaf(a.y, b.y, c.y); return r;
#endif
}

// pack two f32 -> bf16x2 by truncation (1 v_perm_b32); lo in low half
__device__ __forceinline__ unsigned bf16pk(float lo, float hi) {
    return __builtin_amdgcn_perm(__float_as_uint(hi), __float_as_uint(lo), 0x07060302u);
}
__device__ __forceinline__ unsigned short bf16rne(float f) {
    unsigned u = __float_as_uint(f);
    return (unsigned short)((u + 0x7FFFu + ((u >> 16) & 1u)) >> 16);
}

// ---- k_prep_all: 512 blocks.
//  [0,256):   V -> VtA4 MFMA A-fragments (bf16 RNE), d-tile of 4
//  [256,384): W -> WtL = W^T * log2e   (64x64 LDS tiles)
//  [384,512): x -> xt  = x^T           (64x64 LDS tiles)
__global__ __launch_bounds__(256) void k_prep_all(
        const float* __restrict__ V, const float* __restrict__ W,
        const float* __restrict__ x, unsigned short* __restrict__ VtA4,
        float* __restrict__ WtL, float* __restrict__ xt) {
    __shared__ char smem[17408];
    const int bid = blockIdx.x;
    if (bid < 256) {
        unsigned short* tile = (unsigned short*)smem;   // 16 KiB
        const int d0 = bid * 4;
        const int dd = threadIdx.x & 3;
        const int hb0 = threadIdx.x >> 2;
#pragma unroll
        for (int p = 0; p < 8; ++p) {
            int h = p * 64 + hb0;
            float4 v = *(const float4*)(V + ((size_t)h * Dv + d0 + dd) * Cv);
            int hb = h >> 5, q = (h >> 3) & 3, j = h & 7;
            int base = ((dd * 16 + hb) * 16 + q * 4) * 8 + j;
            tile[base + 0]  = bf16rne(v.x);
            tile[base + 8]  = bf16rne(v.y);
            tile[base + 16] = bf16rne(v.z);
            tile[base + 24] = bf16rne(v.w);
        }
        __syncthreads();
        uint4* dst = (uint4*)(VtA4 + (size_t)d0 * 2048);
        const uint4* src = (const uint4*)tile;
        for (int t = threadIdx.x; t < 1024; t += 256) dst[t] = src[t];
    } else {
        float (*t)[65] = (float (*)[65])smem;           // 64x65 floats
        const int mb   = (bid - 256) >> 7;              // 0: W, 1: x
        const int tile = (bid - 256) & 127;
        const int tr   = tile >> 4;
        const int tc   = tile & 15;
        const float* src = mb ? x : W;
        float* dst       = mb ? xt : WtL;
        const float scale = mb ? 1.0f : L2E;
        const int lx = threadIdx.x & 15;
        const int ly = threadIdx.x >> 4;
#pragma unroll
        for (int r = 0; r < 64; r += 16) {
            int row = r + ly;
            float4 v = *(const float4*)(src + (size_t)(tr * 64 + row) * Dv + tc * 64 + lx * 4);
            t[row][lx * 4 + 0] = v.x;
            t[row][lx * 4 + 1] = v.y;
            t[row][lx * 4 + 2] = v.z;
            t[row][lx * 4 + 3] = v.w;
        }
        __syncthreads();
#pragma unroll
        for (int r = 0; r < 64; r += 16) {
            int row = r + ly;
            float4 o = make_float4(t[lx * 4 + 0][row] * scale,
                                   t[lx * 4 + 1][row] * scale,
                                   t[lx * 4 + 2][row] * scale,
                                   t[lx * 4 + 3][row] * scale);
            *(float4*)(dst + (size_t)(tc * 64 + row) * 512 + tr * 64 + lx * 4) = o;
        }
    }
}

// ---- k_partial: P[k][b][h] = sum_{d in chunk k} x[b,d]*WtL[d][h] (half out)
// grid = Kv * (Bv/8) = 4096 blocks x 512 threads (h); 8 batches per block.
__global__ __launch_bounds__(512) void k_partial(const float* __restrict__ x,
                          const float* __restrict__ WtL, __half* __restrict__ P) {
    int k  = blockIdx.x >> 6;
    int bg = blockIdx.x & 63;
    int h  = threadIdx.x;
    int d0 = k * DCv;

    __shared__ float xs[DCv * 8];
    if (threadIdx.x < DCv * 8) {
        int g = threadIdx.x & 7;    // batch in group of 8
        int j = threadIdx.x >> 3;   // d in chunk
        xs[j * 8 + g] = x[(size_t)(bg * 8 + g) * Dv + d0 + j];
    }
    __syncthreads();

    float acc[8];
#pragma unroll
    for (int g = 0; g < 8; ++g) acc[g] = 0.0f;

    const float* wp = WtL + (size_t)d0 * Hv + h;
#pragma unroll
    for (int j = 0; j < DCv; ++j) {
        float wv = wp[(size_t)j * Hv];
        const float4 x0 = *(const float4*)(xs + j * 8);
        const float4 x1 = *(const float4*)(xs + j * 8 + 4);
        acc[0] = fmaf(x0.x, wv, acc[0]);
        acc[1] = fmaf(x0.y, wv, acc[1]);
        acc[2] = fmaf(x0.z, wv, acc[2]);
        acc[3] = fmaf(x0.w, wv, acc[3]);
        acc[4] = fmaf(x1.x, wv, acc[4]);
        acc[5] = fmaf(x1.y, wv, acc[5]);
        acc[6] = fmaf(x1.z, wv, acc[6]);
        acc[7] = fmaf(x1.w, wv, acc[7]);
    }
#pragma unroll
    for (int g = 0; g < 8; ++g)
        P[((size_t)k * Bv + bg * 8 + g) * Hv + h] = __float2half(acc[g]);
}

// ---- k_prefix: in-place exclusive prefix over chunks (half), seeded c*log2e.
// Same thread reads-then-writes each element: race-free in place.
__global__ void k_prefix(__half* __restrict__ A0, const float* __restrict__ cbias) {
    int gid = blockIdx.x * blockDim.x + threadIdx.x;   // B*H
    int h = gid & (Hv - 1);
    int bi = gid >> 9;
    float run = cbias[h] * L2E;
    __half* p = A0 + (size_t)bi * Hv + h;
#pragma unroll 4
    for (int k = 0; k < Kv; ++k) {
        float t = __half2float(p[(size_t)k * Bv * Hv]);
        p[(size_t)k * Bv * Hv] = __float2half(run);
        run += t;
    }
}

// ---- k_main: grid Kv*32 = 2048 blocks of 128 (2 waves = 2 x 256-h slices) ----
__global__ __launch_bounds__(128) void k_main(
        const float* __restrict__ xt, const float* __restrict__ bbias,
        const unsigned short* __restrict__ VtA4, const float* __restrict__ WtL,
        const __half* __restrict__ A0, float* __restrict__ out) {
    const int k    = blockIdx.x >> 5;    // chunk
    const int bg   = blockIdx.x & 31;    // 16-batch group
    const int wv   = threadIdx.x >> 6;   // h-half (0: h<256) AND step role
    const int lane = threadIdx.x & 63;
    const int bl   = lane & 15;          // batch col (B-op) / class row (A-op)
    const int quad = lane >> 4;
    const int b    = bg * 16 + bl;
    const int d0   = k * DCv;

    __shared__ f32x4 red[2][2][2][64];   // [dbuf][step][hhalf][lane], 8 KiB

    // a state: h = wv*256 + kb*32 + quad*8 + {0..7}, as v2f pairs (f32)
    v2f a2[32];
    {
        const __half* ap = A0 + ((size_t)k * Bv + b) * Hv + wv * 256 + quad * 8;
#pragma unroll
        for (int kb = 0; kb < 8; ++kb) {
            union { uint4 u; __half2 h2[4]; } t;
            t.u = *(const uint4*)(ap + kb * 32);
#pragma unroll
            for (int tt = 0; tt < 4; ++tt) {
                float2 f = __half22float2(t.h2[tt]);
                a2[kb * 4 + tt] = (v2f){f.x, f.y};
            }
        }
    }

    const int blc = (bl < 4) ? bl : 0;   // clamp A-row (garbage rows discarded)
    const unsigned short* vp = VtA4 + (((size_t)d0 * 16 + wv * 8) * 16 + quad * 4 + blc) * 8;
    const float* wp = WtL + (size_t)d0 * Hv + wv * 256 + quad * 8;
    const float* xp = xt + (size_t)d0 * Bv + b;
    const float* bp = bbias + (d0 + wv) * Cv;
    float* sy = out + (size_t)b * Dv * Cv + (d0 + wv) * Cv;
    float* spp = sy + (size_t)Bv * Dv * Cv;

    for (int i1 = 0; i1 < DCv / 2; ++i1) {
        float xdA = xp[0];
        float xdB = xp[Bv];
        float4 bbv = *(const float4*)bp;   // this wave's step's bias

        // ---- step A: sigmoid + pack + MFMA over 8 h-blocks ----
        f32x4 accA = {0.f, 0.f, 0.f, 0.f};
#pragma unroll
        for (int kb = 0; kb < 8; ++kb) {
            union { unsigned u[4]; short8 s; } cv;
#pragma unroll
            for (int t = 0; t < 4; ++t) {
                v2f aa = a2[kb * 4 + t];
                v2f e; e.x = fexp2(-aa.x); e.y = fexp2(-aa.y);
                v2f q = e + 1.0f;
                cv.u[t] = bf16pk(frcp(q.x), frcp(q.y));
            }
            short8 af = *(const short8*)(vp + kb * 128);
            accA = __builtin_amdgcn_mfma_f32_16x16x32_bf16(af, cv.s, accA, 0, 0, 0);
        }
        v2f xA2 = {xdA, xdA};
#pragma unroll
        for (int kb = 0; kb < 8; ++kb) {
            float4 w0 = *(const float4*)(wp + kb * 32);
            float4 w1 = *(const float4*)(wp + kb * 32 + 4);
            a2[kb*4+0] = fma2(xA2, (v2f){w0.x, w0.y}, a2[kb*4+0]);
            a2[kb*4+1] = fma2(xA2, (v2f){w0.z, w0.w}, a2[kb*4+1]);
            a2[kb*4+2] = fma2(xA2, (v2f){w1.x, w1.y}, a2[kb*4+2]);
            a2[kb*4+3] = fma2(xA2, (v2f){w1.z, w1.w}, a2[kb*4+3]);
        }

        // ---- step B ----
        f32x4 accB = {0.f, 0.f, 0.f, 0.f};
#pragma unroll
        for (int kb = 0; kb < 8; ++kb) {
            union { unsigned u[4]; short8 s; } cv;
#pragma unroll
            for (int t = 0; t < 4; ++t) {
                v2f aa = a2[kb * 4 + t];
                v2f e; e.x = fexp2(-aa.x); e.y = fexp2(-aa.y);
                v2f q = e + 1.0f;
                cv.u[t] = bf16pk(frcp(q.x), frcp(q.y));
            }
            short8 af = *(const short8*)(vp + 2048 + kb * 128);
            accB = __builtin_amdgcn_mfma_f32_16x16x32_bf16(af, cv.s, accB, 0, 0, 0);
        }
        v2f xB2 = {xdB, xdB};
#pragma unroll
        for (int kb = 0; kb < 8; ++kb) {
            float4 w0 = *(const float4*)(wp + Hv + kb * 32);
            float4 w1 = *(const float4*)(wp + Hv + kb * 32 + 4);
            a2[kb*4+0] = fma2(xB2, (v2f){w0.x, w0.y}, a2[kb*4+0]);
            a2[kb*4+1] = fma2(xB2, (v2f){w0.z, w0.w}, a2[kb*4+1]);
            a2[kb*4+2] = fma2(xB2, (v2f){w1.x, w1.y}, a2[kb*4+2]);
            a2[kb*4+3] = fma2(xB2, (v2f){w1.z, w1.w}, a2[kb*4+3]);
        }

        // ---- 2-wave reduce: one barrier per pair ----
        red[i1 & 1][0][wv][lane] = accA;
        red[i1 & 1][1][wv][lane] = accB;
        __syncthreads();

        // wave wv handles step wv's epilogue (y AND p)
        f32x4 s = red[i1 & 1][wv][0][lane] + red[i1 & 1][wv][1][lane];
        float w0 = s.x + bbv.x;
        float w1 = s.y + bbv.y;
        float w2 = s.z + bbv.z;
        float w3 = s.w + bbv.w;
        float mx = fmaxf(fmaxf(w0, w1), fmaxf(w2, w3));
        float e0 = fexp2((w0 - mx) * L2E);
        float e1 = fexp2((w1 - mx) * L2E);
        float e2 = fexp2((w2 - mx) * L2E);
        float e3 = fexp2((w3 - mx) * L2E);
        float lse = mx + flog2(e0 + e1 + e2 + e3) * LN2;
        if (quad == 0) {
            *(float4*)sy  = make_float4(w0, w1, w2, w3);
            *(float4*)spp = make_float4(w0 - lse, w1 - lse, w2 - lse, w3 - lse);
        }

        vp += 2 * 2048;    // 2 d-steps
        wp += 2 * Hv;
        xp += 2 * Bv;
        bp += 2 * Cv;
        sy += 2 * Cv;
        spp += 2 * Cv;
    }
}

extern "C" void kernel_launch(void* const* d_in, const int* in_sizes, int n_in,
                              void* d_out, int out_size, void* d_ws, size_t ws_size,
                              hipStream_t stream) {
    const float* x  = (const float*)d_in[0];   // [B, D]
    const float* V  = (const float*)d_in[1];   // [H, D, C]
    const float* bb = (const float*)d_in[2];   // [D, C]
    const float* W  = (const float*)d_in[3];   // [H, D]
    const float* cb = (const float*)d_in[4];   // [1, H]
    float* out = (float*)d_out;                // y_hat [B*D*C] then p_hat

    char* ws = (char*)d_ws;
    unsigned short* VtA4 = (unsigned short*)ws;                 // 4 MiB
    float* WtL = (float*)(ws + (size_t)4 * 1024 * 1024);        // 2 MiB
    float* xt  = (float*)(ws + (size_t)6 * 1024 * 1024);        // 2 MiB
    __half* A0 = (__half*)(ws + (size_t)8 * 1024 * 1024);       // 32 MiB (Kv*B*H half)

    k_prep_all<<<512, 256, 0, stream>>>(V, W, x, VtA4, WtL, xt);
    k_partial<<<Kv * (Bv / 8), 512, 0, stream>>>(x, WtL, A0);
    k_prefix<<<(Bv * Hv) / 256, 256, 0, stream>>>(A0, cb);
    k_main<<<Kv * 32, 128, 0, stream>>>(xt, bb, VtA4, WtL, A0, out);
}